// Round 1
// baseline (483.125 us; speedup 1.0000x reference)
//
#include <hip/hip_runtime.h>
#include <hip/hip_bf16.h>

// Problem dims (fixed)
#define MROWS 8192     // B*S
#define DMODEL 1024
#define SLEN 2048
#define NHEADS 16
#define DKH 64
#define DGH 19
#define NSPAD 304
#define NSKILL 300
#define KGPAD 320      // Wg K padded to 5*64
#define AGG_LD 320     // Agg leading dim
#define QK_LD 2048     // fused Q|K buffer leading dim
#define VK 320         // Vproj GEMM K (padded 300->320)
#define VLD 384        // Vpad leading dim (padded 304->384, 3x128 tiles)

typedef __attribute__((ext_vector_type(8))) short short8;
typedef __attribute__((ext_vector_type(4))) float floatx4;

__device__ __forceinline__ float bf2f(unsigned short u) {
  union { unsigned int i; float f; } cv;
  cv.i = ((unsigned int)u) << 16;
  return cv.f;
}
__device__ __forceinline__ unsigned short f2bf(float f) {
  __hip_bfloat16 h = __float2bfloat16(f);
  unsigned short u;
  __builtin_memcpy(&u, &h, 2);
  return u;
}

__device__ __forceinline__ void ld8(const float* p, float* v) {
  float4 a = *(const float4*)p;
  float4 b = *((const float4*)p + 1);
  v[0]=a.x; v[1]=a.y; v[2]=a.z; v[3]=a.w;
  v[4]=b.x; v[5]=b.y; v[6]=b.z; v[7]=b.w;
}
__device__ __forceinline__ void st1(float* p, float v) { *p = v; }
__device__ __forceinline__ void st1(__hip_bfloat16* p, float v) {
  unsigned short raw = f2bf(v); __builtin_memcpy(p, &raw, 2);
}
__device__ __forceinline__ void st8(__hip_bfloat16* p, const float* v) {
  ushort4 a, b;
  a.x=f2bf(v[0]); a.y=f2bf(v[1]); a.z=f2bf(v[2]); a.w=f2bf(v[3]);
  b.x=f2bf(v[4]); b.y=f2bf(v[5]); b.z=f2bf(v[6]); b.w=f2bf(v[7]);
  *(ushort4*)p = a;
  *((ushort4*)p + 1) = b;
}

// async global->LDS, 16B per lane
__device__ __forceinline__ void gl_lds16(const void* g, void* l) {
  __builtin_amdgcn_global_load_lds(
      (const __attribute__((address_space(1))) unsigned int*)g,
      (__attribute__((address_space(3))) unsigned int*)l, 16, 0, 0);
}

// ---------------- prep kernels ----------------
__global__ __launch_bounds__(256)
void convert_bf16_kernel(const float* __restrict__ in,
                         __hip_bfloat16* __restrict__ out, int nelem)
{
  int i = (blockIdx.x * 256 + threadIdx.x) * 4;
  if (i < nelem) {
    float4 v = *(const float4*)(in + i);
    ushort4 s;
    s.x = f2bf(v.x); s.y = f2bf(v.y); s.z = f2bf(v.z); s.w = f2bf(v.w);
    *(ushort4*)((__hip_bfloat16*)out + i) = s;
  }
}

// Vin [8192,300] fp32 -> Vb16 [8192,320] bf16, K-pad with zeros.
__global__ __launch_bounds__(256)
void convert_v_kernel(const float* __restrict__ in,
                      __hip_bfloat16* __restrict__ out)
{
  int idx = blockIdx.x * 256 + threadIdx.x;   // 8192*40 threads
  int row = idx / 40;
  int c8  = (idx - row * 40) * 8;
  const float* ip = in + (size_t)row * NSKILL + c8;
  float v[8];
  if (c8 + 8 <= NSKILL) {
    ld8(ip, v);
  } else {
    #pragma unroll
    for (int u = 0; u < 8; u++)
      v[u] = (c8 + u < NSKILL) ? ip[u] : 0.f;
  }
  st8(out + (size_t)row * VK + c8, v);
}

// Wt[n][k] = W[k][n] (bf16); zero outside (k<K, n<Ntrue). Nld = W leading dim.
// grid covers [Kpad x Npad] fully, Npad = gridDim.y*32.
__global__ __launch_bounds__(256)
void transpose_w_kernel(const float* __restrict__ W,
                        __hip_bfloat16* __restrict__ Wt,
                        int K, int Nld, int Ntrue, int Kpad)
{
  __shared__ float t[32][33];
  const int k0 = blockIdx.x * 32;
  const int n0 = blockIdx.y * 32;
  const int tx = threadIdx.x & 31, ty = threadIdx.x >> 5;   // ty 0..7
  #pragma unroll
  for (int i = 0; i < 4; i++) {
    int k = k0 + ty + i*8;
    int nn = n0 + tx;
    t[ty + i*8][tx] = (k < K && nn < Ntrue) ? W[(size_t)k * Nld + nn] : 0.f;
  }
  __syncthreads();
  #pragma unroll
  for (int i = 0; i < 4; i++) {
    int nn = n0 + ty + i*8;
    int kk = k0 + tx;
    st1(Wt + (size_t)nn * Kpad + kk, t[tx][ty + i*8]);
  }
}

// ---------------- MFMA GEMM (B-transposed form) ----------------
// C[M,N] = A[M,K] @ Bt[N,K]^T + bias.  M%128==0, N%128==0, K%64==0.
// A leading dim == K.  128x128 tile, BK=64, 256 threads, global_load_lds
// staging with XOR chunk swizzle (c^(r&7)) -> conflict-free ds_read_b128.
template<typename TC>
__global__ __launch_bounds__(256)
void gemm_mfma_bt(const __hip_bfloat16* __restrict__ A,
                  const __hip_bfloat16* __restrict__ Bt,
                  const float* __restrict__ bias,
                  TC* __restrict__ C, int ldc,
                  int M, int N, int K)
{
  __shared__ __align__(16) short Al[128*64];   // 16KB
  __shared__ __align__(16) short Bl[128*64];   // 16KB
  const int tid  = threadIdx.x;
  const int lane = tid & 63;
  const int wave = tid >> 6;
  const int wy = wave >> 1;
  const int wx = wave & 1;
  const int n    = lane & 15;
  const int quad = lane >> 4;

  const int m0 = blockIdx.y * 128;
  const int n0 = blockIdx.x * 128;

  floatx4 acc[4][4];
  #pragma unroll
  for (int i = 0; i < 4; i++)
    #pragma unroll
    for (int j = 0; j < 4; j++) acc[i][j] = (floatx4){0.f,0.f,0.f,0.f};

  const short* Ag = (const short*)A;
  const short* Bg = (const short*)Bt;

  for (int k0 = 0; k0 < K; k0 += 64) {
    #pragma unroll
    for (int it = 0; it < 4; it++) {
      int ci = it*256 + tid;          // 0..1023
      int r = ci >> 3, c = ci & 7;
      int cs = c ^ (r & 7);
      gl_lds16(Ag + (size_t)(m0 + r) * K + k0 + cs*8, &Al[ci*8]);
    }
    #pragma unroll
    for (int it = 0; it < 4; it++) {
      int ci = it*256 + tid;
      int r = ci >> 3, c = ci & 7;
      int cs = c ^ (r & 7);
      gl_lds16(Bg + (size_t)(n0 + r) * K + k0 + cs*8, &Bl[ci*8]);
    }
    __syncthreads();   // compiler drains vmcnt before s_barrier

    #pragma unroll
    for (int s = 0; s < 2; s++) {
      short8 af[4], bfr[4];
      const int c = s*4 + quad;
      #pragma unroll
      for (int i = 0; i < 4; i++) {
        int r = wy*64 + i*16 + n;
        af[i] = *(const short8*)&Al[(r*8 + (c ^ (r & 7)))*8];
      }
      #pragma unroll
      for (int j = 0; j < 4; j++) {
        int r = wx*64 + j*16 + n;
        bfr[j] = *(const short8*)&Bl[(r*8 + (c ^ (r & 7)))*8];
      }
      #pragma unroll
      for (int i = 0; i < 4; i++)
        #pragma unroll
        for (int j = 0; j < 4; j++)
          acc[i][j] = __builtin_amdgcn_mfma_f32_16x16x32_bf16(af[i], bfr[j], acc[i][j], 0, 0, 0);
    }
    __syncthreads();
  }

  float bj[4];
  #pragma unroll
  for (int j = 0; j < 4; j++) bj[j] = bias[n0 + wx*64 + j*16 + n];
  #pragma unroll
  for (int i = 0; i < 4; i++) {
    #pragma unroll
    for (int r = 0; r < 4; r++) {
      int row = m0 + wy*64 + i*16 + quad*4 + r;
      TC* cp = C + (size_t)row * ldc;
      #pragma unroll
      for (int j = 0; j < 4; j++) {
        int col = n0 + wx*64 + j*16 + n;
        st1(cp + col, acc[i][j][r] + bj[j]);
      }
    }
  }
}

// ================= MFMA flash attention =================
#define ATT_BM 128
#define ATT_BK 64
#define ATT_GRID 1024

__global__ __launch_bounds__(256)
void attn_mfma_kernel(const __hip_bfloat16* __restrict__ Qb,
                      const __hip_bfloat16* __restrict__ Kb,
                      const __hip_bfloat16* __restrict__ Vb,
                      __hip_bfloat16* __restrict__ Agg)
{
  __shared__ __align__(16) short Kf[64*64];
  __shared__ __align__(16) short Vf[32*64];
  __shared__ __align__(16) short Pf[4*2*1024];

  const int tid  = threadIdx.x;
  const int lane = tid & 63;
  const int wave = tid >> 6;
  const int n    = lane & 15;
  const int quad = lane >> 4;

  // bijective XCD swizzle: consecutive logical blocks (same b,h; adjacent qt)
  // land on the same XCD -> K/V tiles stay L2-resident.
  const int raw = blockIdx.x;
  const int gid = (raw & 7) * (ATT_GRID / 8) + (raw >> 3);
  const int qt  = gid & 15;
  const int h   = (gid >> 4) & 15;
  const int b   = gid >> 8;
  const int qbase = qt * ATT_BM;
  const size_t bS = (size_t)b * SLEN;

  short8 qf[2][2];
  #pragma unroll
  for (int rf = 0; rf < 2; rf++)
    #pragma unroll
    for (int ks = 0; ks < 2; ks++) {
      const __hip_bfloat16* qp = Qb + (bS + qbase + wave*32 + rf*16 + n) * QK_LD
                                    + h*DKH + ks*32 + quad*8;
      qf[rf][ks] = *(const short8*)qp;
    }

  floatx4 of[2][2];
  float mrow[2][4], lrow[2][4];
  #pragma unroll
  for (int rf = 0; rf < 2; rf++) {
    #pragma unroll
    for (int cv = 0; cv < 2; cv++) of[rf][cv] = (floatx4){0.f,0.f,0.f,0.f};
    #pragma unroll
    for (int r = 0; r < 4; r++) { mrow[rf][r] = -1e30f; lrow[rf][r] = 0.f; }
  }

  const int ntiles = (qbase + ATT_BM + ATT_BK - 1) / ATT_BK;
  const int wrow_max = qbase + wave*32 + 31;

  for (int kt = 0; kt < ntiles; kt++) {
    const int kbase = kt * ATT_BK;

    #pragma unroll
    for (int it = 0; it < 2; it++) {
      int idx = tid + it*256;
      int key = idx >> 3, ch = idx & 7;
      const __hip_bfloat16* gp = Kb + (bS + kbase + key)*QK_LD + h*DKH + ch*8;
      short8 v = *(const short8*)gp;
      int s = ch >> 2, q = ch & 3, c = key >> 4, nn = key & 15;
      *(short8*)&Kf[((((s*4 + c)*4 + q)*16) + nn)*8] = v;
    }
    #pragma unroll
    for (int it = 0; it < 8; it++) {
      int idx = tid + it*256;
      int key = idx >> 5, dim = idx & 31;
      unsigned short v = 0;
      if (dim < DGH) {
        __builtin_memcpy(&v, Vb + (bS + kbase + key)*VLD + h*DGH + dim, 2);
      }
      int cv = dim >> 4, nn = dim & 15, s = key >> 5, q = (key & 31) >> 3, j = key & 7;
      Vf[((((cv*2 + s)*4 + q)*16) + nn)*8 + j] = (short)v;
    }
    __syncthreads();

    if (kbase <= wrow_max) {
      short8 kfr[4][2];
      #pragma unroll
      for (int cf = 0; cf < 4; cf++)
        #pragma unroll
        for (int s = 0; s < 2; s++)
          kfr[cf][s] = *(const short8*)&Kf[((s*4 + cf)*64 + lane)*8];

      floatx4 sf[2][4];
      __builtin_amdgcn_s_setprio(1);
      #pragma unroll
      for (int rf = 0; rf < 2; rf++)
        #pragma unroll
        for (int cf = 0; cf < 4; cf++) {
          floatx4 a2 = (floatx4){0.f,0.f,0.f,0.f};
          a2 = __builtin_amdgcn_mfma_f32_16x16x32_bf16(qf[rf][0], kfr[cf][0], a2, 0, 0, 0);
          a2 = __builtin_amdgcn_mfma_f32_16x16x32_bf16(qf[rf][1], kfr[cf][1], a2, 0, 0, 0);
          sf[rf][cf] = a2;
        }
      __builtin_amdgcn_s_setprio(0);

      #pragma unroll
      for (int rf = 0; rf < 2; rf++) {
        const int qrow0 = qbase + wave*32 + rf*16 + quad*4;
        #pragma unroll
        for (int cf = 0; cf < 4; cf++) {
          int key = kbase + cf*16 + n;
          #pragma unroll
          for (int r = 0; r < 4; r++) {
            float sv = sf[rf][cf][r] * 0.125f;
            if (key > qrow0 + r) sv = -INFINITY;
            sf[rf][cf][r] = sv;
          }
        }
        float mx[4], rs[4], alpha[4];
        #pragma unroll
        for (int r = 0; r < 4; r++) {
          float m0 = fmaxf(fmaxf(sf[rf][0][r], sf[rf][1][r]),
                           fmaxf(sf[rf][2][r], sf[rf][3][r]));
          m0 = fmaxf(m0, __shfl_xor(m0, 1));
          m0 = fmaxf(m0, __shfl_xor(m0, 2));
          m0 = fmaxf(m0, __shfl_xor(m0, 4));
          m0 = fmaxf(m0, __shfl_xor(m0, 8));
          float mnew = fmaxf(mrow[rf][r], m0);
          alpha[r] = __expf(mrow[rf][r] - mnew);
          mrow[rf][r] = mnew;
          mx[r] = mnew;
        }
        #pragma unroll
        for (int r = 0; r < 4; r++) rs[r] = 0.f;
        #pragma unroll
        for (int cf = 0; cf < 4; cf++)
          #pragma unroll
          for (int r = 0; r < 4; r++) {
            float p = __expf(sf[rf][cf][r] - mx[r]);
            sf[rf][cf][r] = p;
            rs[r] += p;
          }
        #pragma unroll
        for (int r = 0; r < 4; r++) {
          float s0 = rs[r];
          s0 += __shfl_xor(s0, 1);
          s0 += __shfl_xor(s0, 2);
          s0 += __shfl_xor(s0, 4);
          s0 += __shfl_xor(s0, 8);
          lrow[rf][r] = lrow[rf][r] * alpha[r] + s0;
        }
        #pragma unroll
        for (int cv = 0; cv < 2; cv++)
          #pragma unroll
          for (int r = 0; r < 4; r++)
            of[rf][cv][r] *= alpha[r];

        #pragma unroll
        for (int cf = 0; cf < 4; cf++) {
          int s = cf >> 1;
          int q2 = (cf & 1)*2 + (n >> 3);
          int j = n & 7;
          #pragma unroll
          for (int r = 0; r < 4; r++) {
            int off = ((((wave*2 + rf)*2 + s)*4 + q2)*16 + quad*4 + r)*8 + j;
            Pf[off] = (short)f2bf(sf[rf][cf][r]);
          }
        }
      }

      short8 vfr[2][2];
      #pragma unroll
      for (int cv = 0; cv < 2; cv++)
        #pragma unroll
        for (int s = 0; s < 2; s++)
          vfr[cv][s] = *(const short8*)&Vf[((cv*2 + s)*64 + lane)*8];
      __builtin_amdgcn_s_setprio(1);
      #pragma unroll
      for (int rf = 0; rf < 2; rf++) {
        short8 pf0 = *(const short8*)&Pf[(((wave*2 + rf)*2 + 0)*64 + lane)*8];
        short8 pf1 = *(const short8*)&Pf[(((wave*2 + rf)*2 + 1)*64 + lane)*8];
        #pragma unroll
        for (int cv = 0; cv < 2; cv++) {
          floatx4 a2 = of[rf][cv];
          a2 = __builtin_amdgcn_mfma_f32_16x16x32_bf16(pf0, vfr[cv][0], a2, 0, 0, 0);
          a2 = __builtin_amdgcn_mfma_f32_16x16x32_bf16(pf1, vfr[cv][1], a2, 0, 0, 0);
          of[rf][cv] = a2;
        }
      }
      __builtin_amdgcn_s_setprio(0);
    }
    __syncthreads();
  }

  #pragma unroll
  for (int rf = 0; rf < 2; rf++) {
    #pragma unroll
    for (int r = 0; r < 4; r++) {
      float inv = 1.f / lrow[rf][r];
      int row = qbase + wave*32 + rf*16 + quad*4 + r;
      __hip_bfloat16* op = Agg + (bS + row)*AGG_LD + h*DGH;
      #pragma unroll
      for (int cv = 0; cv < 2; cv++) {
        int dim = cv*16 + n;
        if (dim < DGH) st1(op + dim, of[rf][cv][r] * inv);
      }
    }
  }

  // h==15 blocks own pad cols 304..319: zero them so the Wg GEMM never
  // multiplies workspace poison (0 * NaN = NaN).
  if (h == 15) {
    int row = qbase + (tid >> 1);
    int c0 = 304 + (tid & 1) * 8;
    float z[8] = {0.f,0.f,0.f,0.f,0.f,0.f,0.f,0.f};
    st8(Agg + (bS + row)*AGG_LD + c0, z);
  }
}

extern "C" void kernel_launch(void* const* d_in, const int* in_sizes, int n_in,
                              void* d_out, int out_size, void* d_ws, size_t ws_size,
                              hipStream_t stream) {
  const float* X   = (const float*)d_in[0];   // [8192,1024]
  const float* Vin = (const float*)d_in[1];   // [8192,300]
  // d_in[2] = mask (causal triu, structural -> ignored)
  const float* Wq  = (const float*)d_in[3];
  const float* bq  = (const float*)d_in[4];
  const float* Wk  = (const float*)d_in[5];
  const float* bk  = (const float*)d_in[6];
  const float* Wv  = (const float*)d_in[7];
  const float* bv  = (const float*)d_in[8];
  const float* Wg  = (const float*)d_in[9];
  const float* bg  = (const float*)d_in[10];
  const float* Wo  = (const float*)d_in[11];
  const float* bo  = (const float*)d_in[12];
  float* out = (float*)d_out;

  // ws layout (50 MB):
  //  region0 [0,16MB):  Xb; after QK-GEMM reused: Vpad @0 (6MB, ld 384), Agg @6MB
  //  region1+2 [16,48MB): QKbuf [8192,2048] bf16 (Q cols 0..1023, K cols 1024..2047)
  //                       after attention: Ybuf @32MB
  //  region3 [48,50MB): shared W^T scratch (2MB), stream-ordered reuse (Wv, Wg, Wo)
  char* ws = (char*)d_ws;
  __hip_bfloat16* Xb    = (__hip_bfloat16*)(ws);
  __hip_bfloat16* Vpad  = (__hip_bfloat16*)(ws);
  __hip_bfloat16* AggB  = (__hip_bfloat16*)(ws + 6291456);
  __hip_bfloat16* QKbuf = (__hip_bfloat16*)(ws + 16777216);
  __hip_bfloat16* Ybuf  = (__hip_bfloat16*)(ws + 33554432);
  __hip_bfloat16* Wt    = (__hip_bfloat16*)(ws + 50331648);

  // d_out doubles as scratch until the final GEMM overwrites it:
  //  Wtqk bf16 [2048,1024] @0 (4MiB) | bias_qk f32[2048] @4MiB | Vb16 bf16
  //  [8192,320] @4,202,496 (5MiB) | bias_v f32[384] @9,445,376
  char* ob = (char*)d_out;
  __hip_bfloat16* Wtqk   = (__hip_bfloat16*)(ob);
  float*          biasqk = (float*)(ob + 4194304);
  __hip_bfloat16* Vb16   = (__hip_bfloat16*)(ob + 4202496);
  float*          biasv  = (float*)(ob + 9445376);

  dim3 blk(256);
  // X -> bf16; Vin -> bf16 K-padded to 320
  convert_bf16_kernel<<<dim3(8192), blk, 0, stream>>>(X, Xb, MROWS*DMODEL);
  convert_v_kernel<<<dim3(1280), blk, 0, stream>>>(Vin, Vb16);

  // W^T for fused Q|K GEMM + concatenated bias
  transpose_w_kernel<<<dim3(32, 32), blk, 0, stream>>>(Wq, Wtqk, DMODEL, DMODEL, DMODEL, DMODEL);
  transpose_w_kernel<<<dim3(32, 32), blk, 0, stream>>>(Wk, Wtqk + 1024*1024, DMODEL, DMODEL, DMODEL, DMODEL);
  hipMemcpyAsync(biasqk,        bq, DMODEL*sizeof(float), hipMemcpyDeviceToDevice, stream);
  hipMemcpyAsync(biasqk + 1024, bk, DMODEL*sizeof(float), hipMemcpyDeviceToDevice, stream);
  hipMemsetAsync(biasv, 0, VLD*sizeof(float), stream);
  hipMemcpyAsync(biasv, bv, NSKILL*sizeof(float), hipMemcpyDeviceToDevice, stream);

  // [Q|K] = Xb @ [Wq|Wk]^T + [bq|bk]   (one 1024-block launch)
  gemm_mfma_bt<__hip_bfloat16><<<dim3(16, 64), blk, 0, stream>>>(
      Xb, Wtqk, biasqk, QKbuf, QK_LD, MROWS, QK_LD, DMODEL);

  // Vpad = pad(Vin @ Wv + bv): MFMA path, N 304->384, K 300->320.
  // W^T rows n>=300 and k>=300 zeroed -> cols 300..383 of Vpad are exact zeros.
  transpose_w_kernel<<<dim3(10, 12), blk, 0, stream>>>(Wv, Wt, NSKILL, NSKILL, NSKILL, VK);
  gemm_mfma_bt<__hip_bfloat16><<<dim3(3, 64), blk, 0, stream>>>(
      Vb16, Wt, biasv, Vpad, VLD, MROWS, VLD, VK);

  // attention -> Agg [8192,320]: cols 0..303 written, 304..319 zeroed (h==15 blocks)
  attn_mfma_kernel<<<dim3(ATT_GRID), dim3(256), 0, stream>>>(
      QKbuf, QKbuf + 1024, Vpad, AggB);

  // Y = Agg[:, :300] @ Wg + bg   (K=320, Wg^T rows >=300 zeroed)
  transpose_w_kernel<<<dim3(10, 32), blk, 0, stream>>>(Wg, Wt, NSKILL, DMODEL, DMODEL, KGPAD);
  gemm_mfma_bt<__hip_bfloat16><<<dim3(8, 64), blk, 0, stream>>>(
      AggB, Wt, bg, Ybuf, DMODEL, MROWS, DMODEL, KGPAD);

  // out = Y @ Wo^T + bo (fp32 out; overwrites all d_out scratch)
  transpose_w_kernel<<<dim3(32, 32), blk, 0, stream>>>(Wo, Wt, DMODEL, DMODEL, DMODEL, DMODEL);
  gemm_mfma_bt<float><<<dim3(8, 64), blk, 0, stream>>>(
      Ybuf, Wt, bo, out, DMODEL, MROWS, DMODEL, DMODEL);
}

// Round 2
// 356.212 us; speedup vs baseline: 1.3563x; 1.3563x over previous
//
#include <hip/hip_runtime.h>
#include <hip/hip_bf16.h>

// Problem dims (fixed)
#define MROWS 8192     // B*S
#define DMODEL 1024
#define SLEN 2048
#define NHEADS 16
#define DKH 64
#define DGH 19
#define NSPAD 304
#define NSKILL 300
#define KGPAD 320      // Wg K padded to 5*64
#define AGG_LD 320     // Agg leading dim
#define QK_LD 2048     // fused Q|K buffer leading dim
#define VK 320         // Vproj GEMM K (padded 300->320)
#define VLD 384        // Vpad leading dim (padded 304->384, 3x128 tiles)

typedef __attribute__((ext_vector_type(8))) short short8;
typedef __attribute__((ext_vector_type(4))) float floatx4;

__device__ __forceinline__ float bf2f(unsigned short u) {
  union { unsigned int i; float f; } cv;
  cv.i = ((unsigned int)u) << 16;
  return cv.f;
}
__device__ __forceinline__ unsigned short f2bf(float f) {
  __hip_bfloat16 h = __float2bfloat16(f);
  unsigned short u;
  __builtin_memcpy(&u, &h, 2);
  return u;
}

__device__ __forceinline__ void ld8(const float* p, float* v) {
  float4 a = *(const float4*)p;
  float4 b = *((const float4*)p + 1);
  v[0]=a.x; v[1]=a.y; v[2]=a.z; v[3]=a.w;
  v[4]=b.x; v[5]=b.y; v[6]=b.z; v[7]=b.w;
}
__device__ __forceinline__ void st1(float* p, float v) { *p = v; }
__device__ __forceinline__ void st1(__hip_bfloat16* p, float v) {
  unsigned short raw = f2bf(v); __builtin_memcpy(p, &raw, 2);
}
__device__ __forceinline__ void st8(__hip_bfloat16* p, const float* v) {
  ushort4 a, b;
  a.x=f2bf(v[0]); a.y=f2bf(v[1]); a.z=f2bf(v[2]); a.w=f2bf(v[3]);
  b.x=f2bf(v[4]); b.y=f2bf(v[5]); b.z=f2bf(v[6]); b.w=f2bf(v[7]);
  *(ushort4*)p = a;
  *((ushort4*)p + 1) = b;
}

// async global->LDS, 16B per lane
__device__ __forceinline__ void gl_lds16(const void* g, void* l) {
  __builtin_amdgcn_global_load_lds(
      (const __attribute__((address_space(1))) unsigned int*)g,
      (__attribute__((address_space(3))) unsigned int*)l, 16, 0, 0);
}

// ---------------- prep kernels ----------------
__global__ __launch_bounds__(256)
void convert_bf16_kernel(const float* __restrict__ in,
                         __hip_bfloat16* __restrict__ out, int nelem)
{
  int i = (blockIdx.x * 256 + threadIdx.x) * 4;
  if (i < nelem) {
    float4 v = *(const float4*)(in + i);
    ushort4 s;
    s.x = f2bf(v.x); s.y = f2bf(v.y); s.z = f2bf(v.z); s.w = f2bf(v.w);
    *(ushort4*)((__hip_bfloat16*)out + i) = s;
  }
}

// Vin [8192,300] fp32 -> Vb16 [8192,320] bf16, K-pad with zeros.
__global__ __launch_bounds__(256)
void convert_v_kernel(const float* __restrict__ in,
                      __hip_bfloat16* __restrict__ out)
{
  int idx = blockIdx.x * 256 + threadIdx.x;   // 8192*40 threads
  int row = idx / 40;
  int c8  = (idx - row * 40) * 8;
  const float* ip = in + (size_t)row * NSKILL + c8;
  float v[8];
  if (c8 + 8 <= NSKILL) {
    ld8(ip, v);
  } else {
    #pragma unroll
    for (int u = 0; u < 8; u++)
      v[u] = (c8 + u < NSKILL) ? ip[u] : 0.f;
  }
  st8(out + (size_t)row * VK + c8, v);
}

// Wt[n][k] = W[k][n] (bf16); zero outside (k<K, n<Ntrue). Nld = W leading dim.
__global__ __launch_bounds__(256)
void transpose_w_kernel(const float* __restrict__ W,
                        __hip_bfloat16* __restrict__ Wt,
                        int K, int Nld, int Ntrue, int Kpad)
{
  __shared__ float t[32][33];
  const int k0 = blockIdx.x * 32;
  const int n0 = blockIdx.y * 32;
  const int tx = threadIdx.x & 31, ty = threadIdx.x >> 5;   // ty 0..7
  #pragma unroll
  for (int i = 0; i < 4; i++) {
    int k = k0 + ty + i*8;
    int nn = n0 + tx;
    t[ty + i*8][tx] = (k < K && nn < Ntrue) ? W[(size_t)k * Nld + nn] : 0.f;
  }
  __syncthreads();
  #pragma unroll
  for (int i = 0; i < 4; i++) {
    int nn = n0 + ty + i*8;
    int kk = k0 + tx;
    st1(Wt + (size_t)nn * Kpad + kk, t[tx][ty + i*8]);
  }
}

// ---------------- MFMA GEMM (B-transposed form) ----------------
template<typename TC>
__global__ __launch_bounds__(256)
void gemm_mfma_bt(const __hip_bfloat16* __restrict__ A,
                  const __hip_bfloat16* __restrict__ Bt,
                  const float* __restrict__ bias,
                  TC* __restrict__ C, int ldc,
                  int M, int N, int K)
{
  __shared__ __align__(16) short Al[128*64];   // 16KB
  __shared__ __align__(16) short Bl[128*64];   // 16KB
  const int tid  = threadIdx.x;
  const int lane = tid & 63;
  const int wave = tid >> 6;
  const int wy = wave >> 1;
  const int wx = wave & 1;
  const int n    = lane & 15;
  const int quad = lane >> 4;

  const int m0 = blockIdx.y * 128;
  const int n0 = blockIdx.x * 128;

  floatx4 acc[4][4];
  #pragma unroll
  for (int i = 0; i < 4; i++)
    #pragma unroll
    for (int j = 0; j < 4; j++) acc[i][j] = (floatx4){0.f,0.f,0.f,0.f};

  const short* Ag = (const short*)A;
  const short* Bg = (const short*)Bt;

  for (int k0 = 0; k0 < K; k0 += 64) {
    #pragma unroll
    for (int it = 0; it < 4; it++) {
      int ci = it*256 + tid;          // 0..1023
      int r = ci >> 3, c = ci & 7;
      int cs = c ^ (r & 7);
      gl_lds16(Ag + (size_t)(m0 + r) * K + k0 + cs*8, &Al[ci*8]);
    }
    #pragma unroll
    for (int it = 0; it < 4; it++) {
      int ci = it*256 + tid;
      int r = ci >> 3, c = ci & 7;
      int cs = c ^ (r & 7);
      gl_lds16(Bg + (size_t)(n0 + r) * K + k0 + cs*8, &Bl[ci*8]);
    }
    __syncthreads();   // compiler drains vmcnt before s_barrier

    #pragma unroll
    for (int s = 0; s < 2; s++) {
      short8 af[4], bfr[4];
      const int c = s*4 + quad;
      #pragma unroll
      for (int i = 0; i < 4; i++) {
        int r = wy*64 + i*16 + n;
        af[i] = *(const short8*)&Al[(r*8 + (c ^ (r & 7)))*8];
      }
      #pragma unroll
      for (int j = 0; j < 4; j++) {
        int r = wx*64 + j*16 + n;
        bfr[j] = *(const short8*)&Bl[(r*8 + (c ^ (r & 7)))*8];
      }
      #pragma unroll
      for (int i = 0; i < 4; i++)
        #pragma unroll
        for (int j = 0; j < 4; j++)
          acc[i][j] = __builtin_amdgcn_mfma_f32_16x16x32_bf16(af[i], bfr[j], acc[i][j], 0, 0, 0);
    }
    __syncthreads();
  }

  float bj[4];
  #pragma unroll
  for (int j = 0; j < 4; j++) bj[j] = bias[n0 + wx*64 + j*16 + n];
  #pragma unroll
  for (int i = 0; i < 4; i++) {
    #pragma unroll
    for (int r = 0; r < 4; r++) {
      int row = m0 + wy*64 + i*16 + quad*4 + r;
      TC* cp = C + (size_t)row * ldc;
      #pragma unroll
      for (int j = 0; j < 4; j++) {
        int col = n0 + wx*64 + j*16 + n;
        st1(cp + col, acc[i][j][r] + bj[j]);
      }
    }
  }
}

// ================= MFMA flash attention (swapped-operand form) =================
// S^T = mfma(K, Q): lane n owns one q-row; keys live in (cf, quad, r).
// Softmax is lane-local + 2 cross-quad shuffles. P^T re-laid to a B-fragment
// via packed b64 LDS writes. O^T = mfma(V, P^T): rows = dg, cols = q.
#define ATT_BM 128
#define ATT_BK 64
#define ATT_GRID 1024

__global__ __launch_bounds__(256)
void attn_mfma_kernel(const __hip_bfloat16* __restrict__ Qb,
                      const __hip_bfloat16* __restrict__ Kb,
                      const __hip_bfloat16* __restrict__ Vb,
                      __hip_bfloat16* __restrict__ Agg)
{
  __shared__ __align__(16) short Kf[64*64];                       // 8 KB
  __shared__ __align__(16) short Vf[32*64];                       // 4 KB
  __shared__ __align__(16) unsigned int Pl[4][2][2][4][16][4];    // 16 KB [wave][rf][s][quad_t][n][jp]

  const int tid  = threadIdx.x;
  const int lane = tid & 63;
  const int wave = tid >> 6;
  const int n    = lane & 15;
  const int quad = lane >> 4;

  // CU-balanced causal scheduling: under round-robin dispatch, blocks
  // {i, i+256, i+512, i+768} share a CU. This mapping gives them qt values
  // {15-a, 11-a, a, 4+a} (a = (i>>6)&3) -> per-CU work sum is uniform.
  // Bonus: those 4 blocks share (b,h) -> same K/V stream stays L1/L2-hot.
  const int raw = blockIdx.x;
  const int grp = raw >> 6;                         // 0..15
  const int qt  = (grp < 8) ? (15 - grp) : (grp - 8);
  const int bh  = raw & 63;
  const int h   = bh & 15;
  const int b   = bh >> 4;
  const int qbase = qt * ATT_BM;
  const size_t bS = (size_t)b * SLEN;

  // Q fragments (B-operand: col = q = n), pre-scaled by 1/sqrt(64)=0.125
  // (power of 2 -> exact in bf16).
  short8 qf[2][2];
  #pragma unroll
  for (int rf = 0; rf < 2; rf++)
    #pragma unroll
    for (int ks = 0; ks < 2; ks++) {
      const __hip_bfloat16* qp = Qb + (bS + qbase + wave*32 + rf*16 + n) * QK_LD
                                    + h*DKH + ks*32 + quad*8;
      short8 v = *(const short8*)qp;
      #pragma unroll
      for (int e = 0; e < 8; e++) {
        float f = bf2f((unsigned short)v[e]) * 0.125f;
        v[e] = (short)f2bf(f);
      }
      qf[rf][ks] = v;
    }

  floatx4 of[2][2];             // [rf][cv]: O^T rows dg = cv*16+quad*4+r, col q = n
  float mrow[2], lrow[2];
  #pragma unroll
  for (int rf = 0; rf < 2; rf++) {
    #pragma unroll
    for (int cv = 0; cv < 2; cv++) of[rf][cv] = (floatx4){0.f,0.f,0.f,0.f};
    mrow[rf] = -1e30f; lrow[rf] = 0.f;
  }

  const int ntiles = (qbase + ATT_BM + ATT_BK - 1) / ATT_BK;
  const int wrow_max = qbase + wave*32 + 31;

  for (int kt = 0; kt < ntiles; kt++) {
    const int kbase = kt * ATT_BK;

    #pragma unroll
    for (int it = 0; it < 2; it++) {
      int idx = tid + it*256;
      int key = idx >> 3, ch = idx & 7;
      const __hip_bfloat16* gp = Kb + (bS + kbase + key)*QK_LD + h*DKH + ch*8;
      short8 v = *(const short8*)gp;
      int s = ch >> 2, q = ch & 3, c = key >> 4, nn = key & 15;
      *(short8*)&Kf[((((s*4 + c)*4 + q)*16) + nn)*8] = v;
    }
    #pragma unroll
    for (int it = 0; it < 8; it++) {
      int idx = tid + it*256;
      int key = idx >> 5, dim = idx & 31;
      unsigned short v = 0;
      if (dim < DGH) {
        __builtin_memcpy(&v, Vb + (bS + kbase + key)*VLD + h*DGH + dim, 2);
      }
      int cv = dim >> 4, nn = dim & 15, s = key >> 5, q = (key & 31) >> 3, j = key & 7;
      Vf[((((cv*2 + s)*4 + q)*16) + nn)*8 + j] = (short)v;
    }
    __syncthreads();

    if (kbase <= wrow_max) {
      short8 kfr[4][2];         // A-operand: row = key = cf*16 + lane&15
      #pragma unroll
      for (int cf = 0; cf < 4; cf++)
        #pragma unroll
        for (int s = 0; s < 2; s++)
          kfr[cf][s] = *(const short8*)&Kf[((s*4 + cf)*64 + lane)*8];

      floatx4 sf[2][4];         // S^T: row = key-local quad*4+r, col = q = n
      __builtin_amdgcn_s_setprio(1);
      #pragma unroll
      for (int rf = 0; rf < 2; rf++)
        #pragma unroll
        for (int cf = 0; cf < 4; cf++) {
          floatx4 a2 = (floatx4){0.f,0.f,0.f,0.f};
          a2 = __builtin_amdgcn_mfma_f32_16x16x32_bf16(kfr[cf][0], qf[rf][0], a2, 0, 0, 0);
          a2 = __builtin_amdgcn_mfma_f32_16x16x32_bf16(kfr[cf][1], qf[rf][1], a2, 0, 0, 0);
          sf[rf][cf] = a2;
        }
      __builtin_amdgcn_s_setprio(0);

      #pragma unroll
      for (int rf = 0; rf < 2; rf++) {
        const int qrow = qbase + wave*32 + rf*16 + n;
        // mask only tiles straddling the diagonal for this wave/rf
        if (kbase + 63 > qbase + wave*32 + rf*16) {
          #pragma unroll
          for (int cf = 0; cf < 4; cf++)
            #pragma unroll
            for (int r = 0; r < 4; r++) {
              int key = kbase + cf*16 + quad*4 + r;
              if (key > qrow) sf[rf][cf][r] = -INFINITY;
            }
        }
        // lane-local tile max + 2 cross-quad shuffles
        float m0 = sf[rf][0][0];
        #pragma unroll
        for (int cf = 0; cf < 4; cf++)
          #pragma unroll
          for (int r = 0; r < 4; r++) m0 = fmaxf(m0, sf[rf][cf][r]);
        m0 = fmaxf(m0, __shfl_xor(m0, 16));
        m0 = fmaxf(m0, __shfl_xor(m0, 32));
        float mnew = fmaxf(mrow[rf], m0);
        float alpha = __expf(mrow[rf] - mnew);
        mrow[rf] = mnew;
        float rs = 0.f;
        #pragma unroll
        for (int cf = 0; cf < 4; cf++)
          #pragma unroll
          for (int r = 0; r < 4; r++) {
            float p = __expf(sf[rf][cf][r] - mnew);
            sf[rf][cf][r] = p;
            rs += p;
          }
        rs += __shfl_xor(rs, 16);
        rs += __shfl_xor(rs, 32);
        lrow[rf] = lrow[rf] * alpha + rs;
        #pragma unroll
        for (int cv = 0; cv < 2; cv++)
          #pragma unroll
          for (int r = 0; r < 4; r++) of[rf][cv][r] *= alpha;

        // P^T -> bf16 B-fragment layout via packed b64 LDS writes.
        // word (cf,h) holds keys cf*16+quad*4+{2h,2h+1} for q=n; it belongs at
        // fragment slice s=cf>>1, target quad 2*(cf&1)+(quad>>1), jp=2*(quad&1)+h.
        #pragma unroll
        for (int cf = 0; cf < 4; cf++) {
          unsigned int w0 = (unsigned int)f2bf(sf[rf][cf][0])
                          | ((unsigned int)f2bf(sf[rf][cf][1]) << 16);
          unsigned int w1 = (unsigned int)f2bf(sf[rf][cf][2])
                          | ((unsigned int)f2bf(sf[rf][cf][3]) << 16);
          int s   = cf >> 1;
          int qt2 = 2*(cf & 1) + (quad >> 1);
          int jp  = 2*(quad & 1);
          *(uint2*)&Pl[wave][rf][s][qt2][n][jp] = make_uint2(w0, w1);
        }
      }

      short8 vfr[2][2];         // A-operand: row = dg = cv*16 + lane&15
      #pragma unroll
      for (int cv = 0; cv < 2; cv++)
        #pragma unroll
        for (int s = 0; s < 2; s++)
          vfr[cv][s] = *(const short8*)&Vf[((cv*2 + s)*64 + lane)*8];

      __builtin_amdgcn_s_setprio(1);
      #pragma unroll
      for (int rf = 0; rf < 2; rf++) {
        short8 p0 = *(const short8*)&Pl[wave][rf][0][quad][n][0];
        short8 p1 = *(const short8*)&Pl[wave][rf][1][quad][n][0];
        #pragma unroll
        for (int cv = 0; cv < 2; cv++) {
          floatx4 a2 = of[rf][cv];
          a2 = __builtin_amdgcn_mfma_f32_16x16x32_bf16(vfr[cv][0], p0, a2, 0, 0, 0);
          a2 = __builtin_amdgcn_mfma_f32_16x16x32_bf16(vfr[cv][1], p1, a2, 0, 0, 0);
          of[rf][cv] = a2;
        }
      }
      __builtin_amdgcn_s_setprio(0);
    }
    __syncthreads();
  }

  // epilogue: lane n owns q-row qbase+wave*32+rf*16+n; dims dg = cv*16+quad*4+r
  #pragma unroll
  for (int rf = 0; rf < 2; rf++) {
    float inv = 1.f / lrow[rf];
    int row = qbase + wave*32 + rf*16 + n;
    __hip_bfloat16* op = Agg + (bS + row)*AGG_LD + h*DGH;
    #pragma unroll
    for (int cv = 0; cv < 2; cv++)
      #pragma unroll
      for (int r = 0; r < 4; r++) {
        int dim = cv*16 + quad*4 + r;
        if (dim < DGH) st1(op + dim, of[rf][cv][r] * inv);
      }
  }

  // h==15 blocks own pad cols 304..319: zero them so the Wg GEMM never
  // multiplies workspace poison (0 * NaN = NaN).
  if (h == 15) {
    int row = qbase + (tid >> 1);
    int c0 = 304 + (tid & 1) * 8;
    float z[8] = {0.f,0.f,0.f,0.f,0.f,0.f,0.f,0.f};
    st8(Agg + (bS + row)*AGG_LD + c0, z);
  }
}

extern "C" void kernel_launch(void* const* d_in, const int* in_sizes, int n_in,
                              void* d_out, int out_size, void* d_ws, size_t ws_size,
                              hipStream_t stream) {
  const float* X   = (const float*)d_in[0];   // [8192,1024]
  const float* Vin = (const float*)d_in[1];   // [8192,300]
  // d_in[2] = mask (causal triu, structural -> ignored)
  const float* Wq  = (const float*)d_in[3];
  const float* bq  = (const float*)d_in[4];
  const float* Wk  = (const float*)d_in[5];
  const float* bk  = (const float*)d_in[6];
  const float* Wv  = (const float*)d_in[7];
  const float* bv  = (const float*)d_in[8];
  const float* Wg  = (const float*)d_in[9];
  const float* bg  = (const float*)d_in[10];
  const float* Wo  = (const float*)d_in[11];
  const float* bo  = (const float*)d_in[12];
  float* out = (float*)d_out;

  // ws layout (50 MB):
  //  region0 [0,16MB):  Xb; after QK-GEMM reused: Vpad @0 (6MB, ld 384), Agg @6MB
  //  region1+2 [16,48MB): QKbuf [8192,2048] bf16 (Q cols 0..1023, K cols 1024..2047)
  //                       after attention: Ybuf @32MB
  //  region3 [48,50MB): shared W^T scratch (2MB), stream-ordered reuse (Wv, Wg, Wo)
  char* ws = (char*)d_ws;
  __hip_bfloat16* Xb    = (__hip_bfloat16*)(ws);
  __hip_bfloat16* Vpad  = (__hip_bfloat16*)(ws);
  __hip_bfloat16* AggB  = (__hip_bfloat16*)(ws + 6291456);
  __hip_bfloat16* QKbuf = (__hip_bfloat16*)(ws + 16777216);
  __hip_bfloat16* Ybuf  = (__hip_bfloat16*)(ws + 33554432);
  __hip_bfloat16* Wt    = (__hip_bfloat16*)(ws + 50331648);

  // d_out doubles as scratch until the final GEMM overwrites it:
  //  Wtqk bf16 [2048,1024] @0 (4MiB) | bias_qk f32[2048] @4MiB | Vb16 bf16
  //  [8192,320] @4,202,496 (5MiB) | bias_v f32[384] @9,445,376
  char* ob = (char*)d_out;
  __hip_bfloat16* Wtqk   = (__hip_bfloat16*)(ob);
  float*          biasqk = (float*)(ob + 4194304);
  __hip_bfloat16* Vb16   = (__hip_bfloat16*)(ob + 4202496);
  float*          biasv  = (float*)(ob + 9445376);

  dim3 blk(256);
  // X -> bf16; Vin -> bf16 K-padded to 320
  convert_bf16_kernel<<<dim3(8192), blk, 0, stream>>>(X, Xb, MROWS*DMODEL);
  convert_v_kernel<<<dim3(1280), blk, 0, stream>>>(Vin, Vb16);

  // W^T for fused Q|K GEMM + concatenated bias
  transpose_w_kernel<<<dim3(32, 32), blk, 0, stream>>>(Wq, Wtqk, DMODEL, DMODEL, DMODEL, DMODEL);
  transpose_w_kernel<<<dim3(32, 32), blk, 0, stream>>>(Wk, Wtqk + 1024*1024, DMODEL, DMODEL, DMODEL, DMODEL);
  hipMemcpyAsync(biasqk,        bq, DMODEL*sizeof(float), hipMemcpyDeviceToDevice, stream);
  hipMemcpyAsync(biasqk + 1024, bk, DMODEL*sizeof(float), hipMemcpyDeviceToDevice, stream);
  hipMemsetAsync(biasv, 0, VLD*sizeof(float), stream);
  hipMemcpyAsync(biasv, bv, NSKILL*sizeof(float), hipMemcpyDeviceToDevice, stream);

  // [Q|K] = Xb @ [Wq|Wk]^T + [bq|bk]   (one 1024-block launch)
  gemm_mfma_bt<__hip_bfloat16><<<dim3(16, 64), blk, 0, stream>>>(
      Xb, Wtqk, biasqk, QKbuf, QK_LD, MROWS, QK_LD, DMODEL);

  // Vpad = pad(Vin @ Wv + bv): MFMA path, N 304->384, K 300->320.
  transpose_w_kernel<<<dim3(10, 12), blk, 0, stream>>>(Wv, Wt, NSKILL, NSKILL, NSKILL, VK);
  gemm_mfma_bt<__hip_bfloat16><<<dim3(3, 64), blk, 0, stream>>>(
      Vb16, Wt, biasv, Vpad, VLD, MROWS, VLD, VK);

  // attention -> Agg [8192,320]: cols 0..303 written, 304..319 zeroed (h==15 blocks)
  attn_mfma_kernel<<<dim3(ATT_GRID), dim3(256), 0, stream>>>(
      QKbuf, QKbuf + 1024, Vpad, AggB);

  // Y = Agg[:, :300] @ Wg + bg   (K=320, Wg^T rows >=300 zeroed)
  transpose_w_kernel<<<dim3(10, 32), blk, 0, stream>>>(Wg, Wt, NSKILL, DMODEL, DMODEL, KGPAD);
  gemm_mfma_bt<__hip_bfloat16><<<dim3(8, 64), blk, 0, stream>>>(
      AggB, Wt, bg, Ybuf, DMODEL, MROWS, DMODEL, KGPAD);

  // out = Y @ Wo^T + bo (fp32 out; overwrites all d_out scratch)
  transpose_w_kernel<<<dim3(32, 32), blk, 0, stream>>>(Wo, Wt, DMODEL, DMODEL, DMODEL, DMODEL);
  gemm_mfma_bt<float><<<dim3(8, 64), blk, 0, stream>>>(
      Ybuf, Wt, bo, out, DMODEL, MROWS, DMODEL, DMODEL);
}